// Round 4
// baseline (603.477 us; speedup 1.0000x reference)
//
#include <hip/hip_runtime.h>
#include <hip/hip_bf16.h>

// Pattention fused kernel, round 4: 32m-wide waves (halve k_lds read redundancy),
// XOR-swizzled g_lds (stride 64, no pad). Counted-vmcnt pipeline, 2 barriers/tile.
// out[m,n] = (sqrt(P)/||gelu(X K^T)[m,:]||) * (gelu(X K^T) @ V)[m,n]
// M=16384 (B*T), D=512, P=4096. bf16 MFMA (16x16x32), fp32 accum.

typedef __attribute__((ext_vector_type(8))) short bf16x8;   // 8 bf16 = 4 VGPR
typedef __attribute__((ext_vector_type(4))) float f32x4;    // MFMA C/D

static constexpr int M_TOTAL = 16384;
static constexpr int DDIM    = 512;
static constexpr int PDIM    = 4096;
static constexpr int BM      = 64;    // rows per block
static constexpr int BP      = 64;    // P-tile

#define AS1C(p) ((const __attribute__((address_space(1))) void*)(p))
#define AS3(p)  ((__attribute__((address_space(3))) void*)(p))

__device__ __forceinline__ unsigned short f2bf(float f) {
    union { float f; unsigned u; } v; v.f = f;
    unsigned r = v.u + 0x7FFFu + ((v.u >> 16) & 1u);   // RNE
    return (unsigned short)(r >> 16);
}

// tanh-form GELU: x * sigmoid(2 * x * (c0 + c1 x^2)); |err vs exact| < 1e-3
__device__ __forceinline__ float gelu_f(float x) {
    float t2 = 2.0f * x * (0.7978845608028654f + 0.035677408136300125f * x * x);
    return x / (1.0f + __expf(-t2));
}

// ---------- convert key_tokens fp32 -> bf16 row-major [4096][512] ----------
__global__ void conv_k(const float* __restrict__ kin, unsigned short* __restrict__ kbf) {
    int i = (blockIdx.x * 256 + threadIdx.x) * 4;
    float4 v = *reinterpret_cast<const float4*>(kin + i);
    ushort4 o;
    o.x = f2bf(v.x); o.y = f2bf(v.y); o.z = f2bf(v.z); o.w = f2bf(v.w);
    *reinterpret_cast<ushort4*>(kbf + i) = o;
}

// ---------- convert value_tokens fp32 [4096][512] -> fragment-blocked bf16 ----------
//   vt2[ ((pb*32 + nb)*64 + lane)*8 + j ] = V[ pb*32 + (lane>>4)*8 + j ][ nb*16 + (lane&15) ]
__global__ void conv_vt2(const float* __restrict__ vin, unsigned short* __restrict__ vt2) {
    int tid  = blockIdx.x * 256 + threadIdx.x;  // 262144 total
    int lane = tid & 63;
    int blk  = tid >> 6;
    int nb = blk & 31;
    int pb = blk >> 5;
    int p0 = pb * 32 + ((lane >> 4) << 3);
    int n  = nb * 16 + (lane & 15);
    ushort4 a, b;
    a.x = f2bf(vin[(p0 + 0) * DDIM + n]);
    a.y = f2bf(vin[(p0 + 1) * DDIM + n]);
    a.z = f2bf(vin[(p0 + 2) * DDIM + n]);
    a.w = f2bf(vin[(p0 + 3) * DDIM + n]);
    b.x = f2bf(vin[(p0 + 4) * DDIM + n]);
    b.y = f2bf(vin[(p0 + 5) * DDIM + n]);
    b.z = f2bf(vin[(p0 + 6) * DDIM + n]);
    b.w = f2bf(vin[(p0 + 7) * DDIM + n]);
    *reinterpret_cast<ushort4*>(vt2 + tid * 8 + 0) = a;
    *reinterpret_cast<ushort4*>(vt2 + tid * 8 + 4) = b;
}

// ---------- fused kernel: 256 blocks x 512 threads (8 waves) ----------
// GEMM1 (swapped): wave (mg = w>>2, pg = w&3) computes S^T[p = pg*16..+16][m = mg*32..+32]
//   -> each K fragment read by only 2 waves (the mg pair), vs 4 before.
// GEMM2: wave w owns output cols [64w, 64w+64).
__global__ __launch_bounds__(512, 2) void fused_pattn(
    const float* __restrict__ x,              // [16384][512] fp32
    const unsigned short* __restrict__ kbf,   // [4096][512] bf16 row-major
    const unsigned short* __restrict__ vt2,   // fragment-blocked bf16
    float* __restrict__ out)                  // [16384][512] fp32
{
    // k_lds: LINEAR [64][512] bf16 per buffer; source-pre-swizzled so reads XOR.
    __shared__ unsigned short k_lds[2][BM * DDIM];   // 2 x 65536 B
    // g_lds: [64][64] bf16, 16B-chunk XOR-swizzled: chunk' = chunk ^ (m & 7)
    __shared__ unsigned short g_lds[BM * BP];        // 8192 B
    __shared__ float ss_lds[BM];

    const int tid  = threadIdx.x;
    const int lane = tid & 63;
    const int w    = tid >> 6;       // wave 0..7
    const int mg   = w >> 2;         // GEMM1 m-group (0..1), 32 rows each
    const int pg   = w & 3;          // GEMM1 p-group (0..3), 16 rows each
    const int l15  = lane & 15;
    const int l4   = lane >> 4;
    const int m_base = blockIdx.x * BM;

    if (tid < BM) ss_lds[tid] = 0.0f;

    // ---- prologue: issue stage(0) first so its latency overlaps the X load ----
    {
        #pragma unroll
        for (int i = 0; i < 8; ++i) {
            int r = w * 8 + i;
            const unsigned short* src = kbf + (size_t)r * DDIM + ((lane ^ i) << 3);
            __builtin_amdgcn_global_load_lds(AS1C(src), AS3(&k_lds[0][r * DDIM]), 16, 0, 0);
        }
    }

    // ---- load X fragments once: 2 m-blocks x 16 d-steps, X[mg*32+mb*16+l15][db*32+l4*8+j] ----
    bf16x8 xf[2][16];
    #pragma unroll
    for (int mb = 0; mb < 2; ++mb) {
        const float* xrow = x + (size_t)(m_base + mg * 32 + mb * 16 + l15) * DDIM + l4 * 8;
        #pragma unroll
        for (int db = 0; db < 16; ++db) {
            float4 a = *reinterpret_cast<const float4*>(xrow + db * 32);
            float4 b = *reinterpret_cast<const float4*>(xrow + db * 32 + 4);
            bf16x8 f;
            f[0] = (short)f2bf(a.x); f[1] = (short)f2bf(a.y);
            f[2] = (short)f2bf(a.z); f[3] = (short)f2bf(a.w);
            f[4] = (short)f2bf(b.x); f[5] = (short)f2bf(b.y);
            f[6] = (short)f2bf(b.z); f[7] = (short)f2bf(b.w);
            xf[mb][db] = f;
        }
    }

    f32x4 zero4 = {0.0f, 0.0f, 0.0f, 0.0f};
    f32x4 oacc[4][4];
    #pragma unroll
    for (int i = 0; i < 4; ++i)
        #pragma unroll
        for (int j = 0; j < 4; ++j) oacc[i][j] = zero4;
    float ss[2] = {0.0f, 0.0f};   // lane-local sum g^2 for m = mg*32 + mb*16 + l15

    int b = 0;
    #pragma unroll 1
    for (int pt = 0; pt < PDIM / BP; ++pt) {
        // ---- A: prefetch V fragments for THIS tile into registers (8 x 16B) ----
        bf16x8 bg[8];
        {
            const int pb0 = pt * 2;
            #pragma unroll
            for (int ks = 0; ks < 2; ++ks)
                #pragma unroll
                for (int nf = 0; nf < 4; ++nf)
                    bg[ks * 4 + nf] = *reinterpret_cast<const bf16x8*>(
                        vt2 + ((size_t)((pb0 + ks) * 32 + w * 4 + nf) * 64 + lane) * 8);
        }

        // ---- B: issue stage(t+1) into the other buffer (wraps on last iter; harmless) ----
        {
            const int P0n = ((pt + 1) & 63) * BP;
            #pragma unroll
            for (int i = 0; i < 8; ++i) {
                int r = w * 8 + i;
                const unsigned short* src = kbf + (size_t)(P0n + r) * DDIM + ((lane ^ i) << 3);
                __builtin_amdgcn_global_load_lds(AS1C(src), AS3(&k_lds[b ^ 1][r * DDIM]), 16, 0, 0);
            }
        }

        // ---- C/D: my stage(t) landed (keep bg(t)+stage(t+1) in flight), then all waves' ----
        asm volatile("s_waitcnt vmcnt(16)" ::: "memory");
        __builtin_amdgcn_s_barrier();

        // ---- E: GEMM1 swapped: sacc[mb] = S^T (p = pg*16+l4*4+r, m = mg*32+mb*16+l15) ----
        // One k-fragment load feeds 2 MFMAs (mb=0,1): k_lds read traffic halved vs r3.
        f32x4 sacc[2]; sacc[0] = zero4; sacc[1] = zero4;
        const int swz  = (l15 & 7) << 3;                // elem XOR for this lane's K rows
        const int rowp = pg * 16 + l15;                 // K row (p) this lane reads
        const unsigned short* kb = &k_lds[b][0];
        __builtin_amdgcn_s_setprio(1);
        #pragma unroll
        for (int db = 0; db < 16; ++db) {
            int cole = ((db << 5) | (l4 << 3)) ^ swz;
            bf16x8 kv = *reinterpret_cast<const bf16x8*>(kb + rowp * DDIM + cole);
            sacc[0] = __builtin_amdgcn_mfma_f32_16x16x32_bf16(kv, xf[0][db], sacc[0], 0, 0, 0);
            sacc[1] = __builtin_amdgcn_mfma_f32_16x16x32_bf16(kv, xf[1][db], sacc[1], 0, 0, 0);
        }
        __builtin_amdgcn_s_setprio(0);

        // ---- F: GELU + lane-local sumsq + packed b64 g-writes (chunk-XOR swizzled) ----
        #pragma unroll
        for (int mb = 0; mb < 2; ++mb) {
            float g0 = gelu_f(sacc[mb][0]);
            float g1 = gelu_f(sacc[mb][1]);
            float g2 = gelu_f(sacc[mb][2]);
            float g3 = gelu_f(sacc[mb][3]);
            ss[mb] += g0 * g0 + g1 * g1 + g2 * g2 + g3 * g3;
            unsigned d0 = (unsigned)f2bf(g0) | ((unsigned)f2bf(g1) << 16);
            unsigned d1 = (unsigned)f2bf(g2) | ((unsigned)f2bf(g3) << 16);
            int m_l   = mg * 32 + mb * 16 + l15;
            int chunk = (pg << 1) | (l4 >> 1);          // (p_l >> 3), p_l = pg*16 + l4*4
            int elem  = (((chunk ^ (l15 & 7)) << 3) | ((l4 & 1) << 2));
            *reinterpret_cast<uint2*>(&g_lds[m_l * BP + elem]) = make_uint2(d0, d1);
        }
        asm volatile("s_waitcnt lgkmcnt(0)" ::: "memory");
        __builtin_amdgcn_s_barrier();

        // ---- H: GEMM2  O += g @ V  (ag from swizzled LDS, bg already in regs) ----
        __builtin_amdgcn_s_setprio(1);
        #pragma unroll
        for (int ks = 0; ks < 2; ++ks) {
            bf16x8 ag[4];
            #pragma unroll
            for (int mf = 0; mf < 4; ++mf) {
                int chunk = ((ks << 2) | l4) ^ (l15 & 7);
                ag[mf] = *reinterpret_cast<const bf16x8*>(
                    &g_lds[(mf * 16 + l15) * BP + (chunk << 3)]);
            }
            #pragma unroll
            for (int mf = 0; mf < 4; ++mf)
                #pragma unroll
                for (int nf = 0; nf < 4; ++nf)
                    oacc[mf][nf] = __builtin_amdgcn_mfma_f32_16x16x32_bf16(
                        ag[mf], bg[ks * 4 + nf], oacc[mf][nf], 0, 0, 0);
        }
        __builtin_amdgcn_s_setprio(0);

        b ^= 1;
    }

    // ---- sumsq: reduce across the 4 lane-groups sharing each row, then across pg waves ----
    #pragma unroll
    for (int mb = 0; mb < 2; ++mb) {
        float v = ss[mb];
        v += __shfl_xor(v, 16, 64);
        v += __shfl_xor(v, 32, 64);
        if (l4 == 0) atomicAdd(&ss_lds[mg * 32 + mb * 16 + l15], v);
    }
    __syncthreads();   // ss ready; also drains the dangling wrap-stage

    // ---- epilogue: out = O * sqrt(P)/sqrt(ss) ----
    #pragma unroll
    for (int mf = 0; mf < 4; ++mf) {
        #pragma unroll
        for (int r = 0; r < 4; ++r) {
            int m_l = mf * 16 + l4 * 4 + r;
            float scale = 64.0f * rsqrtf(ss_lds[m_l]);
            float* orow = out + (size_t)(m_base + m_l) * DDIM + w * 64 + l15;
            #pragma unroll
            for (int nf = 0; nf < 4; ++nf)
                orow[nf * 16] = oacc[mf][nf][r] * scale;
        }
    }
}

extern "C" void kernel_launch(void* const* d_in, const int* in_sizes, int n_in,
                              void* d_out, int out_size, void* d_ws, size_t ws_size,
                              hipStream_t stream) {
    const float* x = (const float*)d_in[0];   // [4,4096,512] = [16384][512]
    const float* k = (const float*)d_in[1];   // [4096][512]
    const float* v = (const float*)d_in[2];   // [4096][512]
    float* out = (float*)d_out;               // [16384][512]

    unsigned short* kbf = (unsigned short*)d_ws;            // 4 MB
    unsigned short* vt2 = kbf + (size_t)PDIM * DDIM;        // 4 MB

    conv_k  <<<dim3(2048), dim3(256), 0, stream>>>(k, kbf);
    conv_vt2<<<dim3(1024), dim3(256), 0, stream>>>(v, vt2);
    fused_pattn<<<dim3(M_TOTAL / BM), dim3(512), 0, stream>>>(x, kbf, vt2, out);
}

// Round 5
// 190.659 us; speedup vs baseline: 3.1652x; 3.1652x over previous
//
#include <hip/hip_runtime.h>
#include <hip/hip_bf16.h>

// Pattention fused kernel, round 5: producer/consumer wave specialization.
// Team A (waves 0-3): GEMM1 (swapped, S^T) + GELU + g-write + K staging.
// Team B (waves 4-7): GEMM2 (O += g V) + epilogue.
// 1 barrier per slot; double-buffered k_lds and g_lds.
// out[m,n] = (sqrt(P)/||gelu(X K^T)[m,:]||) * (gelu(X K^T) @ V)[m,n]
// M=16384 (B*T), D=512, P=4096. bf16 MFMA (16x16x32), fp32 accum.

typedef __attribute__((ext_vector_type(8))) short bf16x8;   // 8 bf16 = 4 VGPR
typedef __attribute__((ext_vector_type(4))) float f32x4;    // MFMA C/D

static constexpr int M_TOTAL = 16384;
static constexpr int DDIM    = 512;
static constexpr int PDIM    = 4096;
static constexpr int BM      = 64;    // rows per block
static constexpr int BP      = 64;    // P-tile
static constexpr int GPAD    = 72;    // g_lds row elems (64 + 8) -> 144B, 2-way banks (free)

#define AS1C(p) ((const __attribute__((address_space(1))) void*)(p))
#define AS3(p)  ((__attribute__((address_space(3))) void*)(p))

__device__ __forceinline__ unsigned short f2bf(float f) {
    union { float f; unsigned u; } v; v.f = f;
    unsigned r = v.u + 0x7FFFu + ((v.u >> 16) & 1u);   // RNE
    return (unsigned short)(r >> 16);
}

// tanh-form GELU: x * sigmoid(2 * x * (c0 + c1 x^2)); |err vs exact| < 1e-3
__device__ __forceinline__ float gelu_f(float x) {
    float t2 = 2.0f * x * (0.7978845608028654f + 0.035677408136300125f * x * x);
    return x / (1.0f + __expf(-t2));
}

// ---------- convert key_tokens fp32 -> bf16 row-major [4096][512] ----------
__global__ void conv_k(const float* __restrict__ kin, unsigned short* __restrict__ kbf) {
    int i = (blockIdx.x * 256 + threadIdx.x) * 4;
    float4 v = *reinterpret_cast<const float4*>(kin + i);
    ushort4 o;
    o.x = f2bf(v.x); o.y = f2bf(v.y); o.z = f2bf(v.z); o.w = f2bf(v.w);
    *reinterpret_cast<ushort4*>(kbf + i) = o;
}

// ---------- convert value_tokens fp32 [4096][512] -> fragment-blocked bf16 ----------
//   vt2[ ((pb*32 + nb)*64 + lane)*8 + j ] = V[ pb*32 + (lane>>4)*8 + j ][ nb*16 + (lane&15) ]
__global__ void conv_vt2(const float* __restrict__ vin, unsigned short* __restrict__ vt2) {
    int tid  = blockIdx.x * 256 + threadIdx.x;  // 262144 total
    int lane = tid & 63;
    int blk  = tid >> 6;
    int nb = blk & 31;
    int pb = blk >> 5;
    int p0 = pb * 32 + ((lane >> 4) << 3);
    int n  = nb * 16 + (lane & 15);
    ushort4 a, b;
    a.x = f2bf(vin[(p0 + 0) * DDIM + n]);
    a.y = f2bf(vin[(p0 + 1) * DDIM + n]);
    a.z = f2bf(vin[(p0 + 2) * DDIM + n]);
    a.w = f2bf(vin[(p0 + 3) * DDIM + n]);
    b.x = f2bf(vin[(p0 + 4) * DDIM + n]);
    b.y = f2bf(vin[(p0 + 5) * DDIM + n]);
    b.z = f2bf(vin[(p0 + 6) * DDIM + n]);
    b.w = f2bf(vin[(p0 + 7) * DDIM + n]);
    *reinterpret_cast<ushort4*>(vt2 + tid * 8 + 0) = a;
    *reinterpret_cast<ushort4*>(vt2 + tid * 8 + 4) = b;
}

// ---------- fused kernel: 256 blocks x 512 threads (8 waves, 2 teams) ----------
__global__ __launch_bounds__(512, 1) void fused_pattn(
    const float* __restrict__ x,              // [16384][512] fp32
    const unsigned short* __restrict__ kbf,   // [4096][512] bf16 row-major
    const unsigned short* __restrict__ vt2,   // fragment-blocked bf16
    float* __restrict__ out)                  // [16384][512] fp32
{
    // k_lds: LINEAR [64][512] bf16 per buffer; source-pre-swizzled so reads XOR.
    __shared__ unsigned short k_lds[2][BM * DDIM];   // 2 x 65536 B
    __shared__ unsigned short g_lds[2][BM * GPAD];   // 2 x  9216 B
    __shared__ float ss_lds[BM];                     // 256 B   (total 149.5 KB)

    const int tid  = threadIdx.x;
    const int lane = tid & 63;
    const int w    = tid >> 6;       // wave 0..7
    const int l15  = lane & 15;
    const int l4   = lane >> 4;
    const int m_base = blockIdx.x * BM;

    if (tid < BM) ss_lds[tid] = 0.0f;

    if (w < 4) {
        // ================= TEAM A: GEMM1 + GELU + staging =================
        const int mg = w >> 1;       // m-group (0..1): rows mg*32..+32
        const int pg = w & 1;        // p-group (0..1): K rows pg*32..+32

        // prologue: stage k(0). Wave stages 16 rows: r = w*16 + i.
        #pragma unroll
        for (int i = 0; i < 16; ++i) {
            int r = w * 16 + i;
            const unsigned short* src = kbf + (size_t)r * DDIM + ((lane ^ (i & 7)) << 3);
            __builtin_amdgcn_global_load_lds(AS1C(src), AS3(&k_lds[0][r * DDIM]), 16, 0, 0);
        }

        // load X fragments: X[mg*32 + mb*16 + l15][db*32 + l4*8 + j]  (128 VGPR)
        bf16x8 xf0[16], xf1[16];
        #pragma unroll
        for (int mb = 0; mb < 2; ++mb) {
            const float* xrow = x + (size_t)(m_base + mg * 32 + mb * 16 + l15) * DDIM + l4 * 8;
            #pragma unroll
            for (int db = 0; db < 16; ++db) {
                float4 a = *reinterpret_cast<const float4*>(xrow + db * 32);
                float4 bq = *reinterpret_cast<const float4*>(xrow + db * 32 + 4);
                bf16x8 f;
                f[0] = (short)f2bf(a.x);  f[1] = (short)f2bf(a.y);
                f[2] = (short)f2bf(a.z);  f[3] = (short)f2bf(a.w);
                f[4] = (short)f2bf(bq.x); f[5] = (short)f2bf(bq.y);
                f[6] = (short)f2bf(bq.z); f[7] = (short)f2bf(bq.w);
                if (mb == 0) xf0[db] = f; else xf1[db] = f;
            }
        }
        asm volatile("s_waitcnt vmcnt(0)" ::: "memory");
        __builtin_amdgcn_s_barrier();                       // instance 0

        f32x4 zero4 = {0.0f, 0.0f, 0.0f, 0.0f};
        float ss[2] = {0.0f, 0.0f};
        const int swz = (l15 & 7) << 3;

        #pragma unroll 1
        for (int t = 0; t < PDIM / BP; ++t) {
            // issue stage(t+1) into other buffer (wraps on last iter; harmless)
            {
                const int P0n = ((t + 1) & 63) * BP;
                #pragma unroll
                for (int i = 0; i < 16; ++i) {
                    int r = w * 16 + i;
                    const unsigned short* src =
                        kbf + (size_t)(P0n + r) * DDIM + ((lane ^ (i & 7)) << 3);
                    __builtin_amdgcn_global_load_lds(
                        AS1C(src), AS3(&k_lds[(t + 1) & 1][r * DDIM]), 16, 0, 0);
                }
            }

            // GEMM1 swapped: sacc[pf][mb] = S^T (p = pg*32+pf*16+l4*4+r, m = mg*32+mb*16+l15)
            f32x4 sacc00 = zero4, sacc01 = zero4, sacc10 = zero4, sacc11 = zero4;
            const unsigned short* kb = &k_lds[t & 1][0];
            __builtin_amdgcn_s_setprio(1);
            #pragma unroll
            for (int db = 0; db < 16; ++db) {
                int cole = ((db << 5) | (l4 << 3)) ^ swz;
                bf16x8 kv0 = *reinterpret_cast<const bf16x8*>(
                    kb + (pg * 32 + l15) * DDIM + cole);
                bf16x8 kv1 = *reinterpret_cast<const bf16x8*>(
                    kb + (pg * 32 + 16 + l15) * DDIM + cole);
                sacc00 = __builtin_amdgcn_mfma_f32_16x16x32_bf16(kv0, xf0[db], sacc00, 0, 0, 0);
                sacc01 = __builtin_amdgcn_mfma_f32_16x16x32_bf16(kv0, xf1[db], sacc01, 0, 0, 0);
                sacc10 = __builtin_amdgcn_mfma_f32_16x16x32_bf16(kv1, xf0[db], sacc10, 0, 0, 0);
                sacc11 = __builtin_amdgcn_mfma_f32_16x16x32_bf16(kv1, xf1[db], sacc11, 0, 0, 0);
            }
            __builtin_amdgcn_s_setprio(0);

            // GELU + lane-local sumsq + packed b64 g-writes into g_lds[t&1]
            unsigned short* gb = &g_lds[t & 1][0];
            #pragma unroll
            for (int pf = 0; pf < 2; ++pf) {
                #pragma unroll
                for (int mb = 0; mb < 2; ++mb) {
                    f32x4 sv = (pf == 0) ? (mb == 0 ? sacc00 : sacc01)
                                         : (mb == 0 ? sacc10 : sacc11);
                    float g0 = gelu_f(sv[0]);
                    float g1 = gelu_f(sv[1]);
                    float g2 = gelu_f(sv[2]);
                    float g3 = gelu_f(sv[3]);
                    ss[mb] += g0 * g0 + g1 * g1 + g2 * g2 + g3 * g3;
                    unsigned d0 = (unsigned)f2bf(g0) | ((unsigned)f2bf(g1) << 16);
                    unsigned d1 = (unsigned)f2bf(g2) | ((unsigned)f2bf(g3) << 16);
                    int m_l = mg * 32 + mb * 16 + l15;
                    int p_l = pg * 32 + pf * 16 + l4 * 4;
                    *reinterpret_cast<uint2*>(&gb[m_l * GPAD + p_l]) = make_uint2(d0, d1);
                }
            }
            asm volatile("s_waitcnt lgkmcnt(0)" ::: "memory");
            asm volatile("s_waitcnt vmcnt(0)" ::: "memory");   // own stage(t+1) landed
            __builtin_amdgcn_s_barrier();                       // instance t+1
        }

        // sumsq: reduce l4 groups within wave, then across pg pair via LDS atomics
        #pragma unroll
        for (int mb = 0; mb < 2; ++mb) {
            float v = ss[mb];
            v += __shfl_xor(v, 16, 64);
            v += __shfl_xor(v, 32, 64);
            if (l4 == 0) atomicAdd(&ss_lds[mg * 32 + mb * 16 + l15], v);
        }
        asm volatile("s_waitcnt lgkmcnt(0)" ::: "memory");
        __builtin_amdgcn_s_barrier();                           // instance 65
        // Team A done.
    } else {
        // ================= TEAM B: GEMM2 + epilogue =================
        const int bw = w - 4;        // owns output cols [bw*128, bw*128+128)

        // prologue: prefetch bg(0): 16 x b128 V fragments
        bf16x8 bg[16];
        #pragma unroll
        for (int ks = 0; ks < 2; ++ks)
            #pragma unroll
            for (int nf = 0; nf < 8; ++nf)
                bg[ks * 8 + nf] = *reinterpret_cast<const bf16x8*>(
                    vt2 + ((size_t)(ks * 32 + bw * 8 + nf) * 64 + lane) * 8);

        f32x4 zero4 = {0.0f, 0.0f, 0.0f, 0.0f};
        f32x4 oacc[4][8];
        #pragma unroll
        for (int i = 0; i < 4; ++i)
            #pragma unroll
            for (int j = 0; j < 8; ++j) oacc[i][j] = zero4;

        __builtin_amdgcn_s_barrier();                           // instance 0

        #pragma unroll 1
        for (int t = 0; t < PDIM / BP; ++t) {
            __builtin_amdgcn_s_barrier();                       // instance t+1: g(t) ready

            const unsigned short* gb = &g_lds[t & 1][0];
            __builtin_amdgcn_s_setprio(1);
            #pragma unroll
            for (int ks = 0; ks < 2; ++ks) {
                bf16x8 ag[4];
                #pragma unroll
                for (int mf = 0; mf < 4; ++mf)
                    ag[mf] = *reinterpret_cast<const bf16x8*>(
                        &gb[(mf * 16 + l15) * GPAD + ks * 32 + l4 * 8]);
                #pragma unroll
                for (int mf = 0; mf < 4; ++mf)
                    #pragma unroll
                    for (int nf = 0; nf < 8; ++nf)
                        oacc[mf][nf] = __builtin_amdgcn_mfma_f32_16x16x32_bf16(
                            ag[mf], bg[ks * 8 + nf], oacc[mf][nf], 0, 0, 0);
            }
            __builtin_amdgcn_s_setprio(0);

            // prefetch bg(t+1) (wraps on last iter; harmless) — WAR on bg regs,
            // in-flight across the next barrier, compiler inserts the use-waits.
            {
                const int pb0 = ((t + 1) & 63) * 2;
                #pragma unroll
                for (int ks = 0; ks < 2; ++ks)
                    #pragma unroll
                    for (int nf = 0; nf < 8; ++nf)
                        bg[ks * 8 + nf] = *reinterpret_cast<const bf16x8*>(
                            vt2 + ((size_t)((pb0 + ks) * 32 + bw * 8 + nf) * 64 + lane) * 8);
            }
        }

        __builtin_amdgcn_s_barrier();                           // instance 65: ss ready

        // epilogue: out = O * sqrt(P)/sqrt(ss)
        #pragma unroll
        for (int mf = 0; mf < 4; ++mf) {
            #pragma unroll
            for (int r = 0; r < 4; ++r) {
                int m_l = mf * 16 + l4 * 4 + r;
                float scale = 64.0f * rsqrtf(ss_lds[m_l]);
                float* orow = out + (size_t)(m_base + m_l) * DDIM + bw * 128 + l15;
                #pragma unroll
                for (int nf = 0; nf < 8; ++nf)
                    orow[nf * 16] = oacc[mf][nf][r] * scale;
            }
        }
    }
}

extern "C" void kernel_launch(void* const* d_in, const int* in_sizes, int n_in,
                              void* d_out, int out_size, void* d_ws, size_t ws_size,
                              hipStream_t stream) {
    const float* x = (const float*)d_in[0];   // [4,4096,512] = [16384][512]
    const float* k = (const float*)d_in[1];   // [4096][512]
    const float* v = (const float*)d_in[2];   // [4096][512]
    float* out = (float*)d_out;               // [16384][512]

    unsigned short* kbf = (unsigned short*)d_ws;            // 4 MB
    unsigned short* vt2 = kbf + (size_t)PDIM * DDIM;        // 4 MB

    conv_k  <<<dim3(2048), dim3(256), 0, stream>>>(k, kbf);
    conv_vt2<<<dim3(1024), dim3(256), 0, stream>>>(v, vt2);
    fused_pattn<<<dim3(M_TOTAL / BM), dim3(512), 0, stream>>>(x, kbf, vt2, out);
}